// Round 5
// baseline (65.344 us; speedup 1.0000x reference)
//
#include <hip/hip_runtime.h>

#define NB 2048
#define NC 16
#define ND 256
#define OUTW 353
#define THRED 0.8f

// 512-thread blocks (8 waves). Per XCD: 64 sim blocks (4 b each) then 512
// neigh blocks (8 rows each).  8*64*4 = 2048 b, 8*512*8 = 32768 rows.
#define SIMB 64
#define NEIB 512
#define PERX (SIMB + NEIB)
#define NBLK (8 * PERX)

typedef short bf16x8 __attribute__((ext_vector_type(8)));
typedef float f32x4 __attribute__((ext_vector_type(4)));
typedef float f32x4a __attribute__((ext_vector_type(4), aligned(4)));

__device__ __forceinline__ unsigned short f2bf(float x) {   // RNE
    unsigned int u = __float_as_uint(x);
    u += 0x7FFFu + ((u >> 16) & 1u);
    return (unsigned short)(u >> 16);
}

__device__ __forceinline__ bf16x8 cvt8(const float4& a, const float4& b) {
    bf16x8 r;
    r[0] = (short)f2bf(a.x); r[1] = (short)f2bf(a.y);
    r[2] = (short)f2bf(a.z); r[3] = (short)f2bf(a.w);
    r[4] = (short)f2bf(b.x); r[5] = (short)f2bf(b.y);
    r[6] = (short)f2bf(b.z); r[7] = (short)f2bf(b.w);
    return r;
}

__global__ __launch_bounds__(512) void fused_kernel(const float* __restrict__ e,
                                                    const int* __restrict__ nm,
                                                    float* __restrict__ out) {
    __shared__ float lsum[8][16];

    const int xcd = blockIdx.x & 7;
    const int idx = blockIdx.x >> 3;
    const int w   = threadIdx.x >> 6;
    const int l   = threadIdx.x & 63;

    if (idx >= SIMB) {
        // ================= NEIGH role: 1 wave per output row =================
        const int nrow = (xcd * NEIB + (idx - SIMB)) * 8 + w;
        const int b = nrow >> 4, c = nrow & 15;

        // clamped indices (loads always in-range)
        const int bm1 = (b >= 1) ? b - 1 : 0;
        const int bm2 = (b >= 2) ? b - 2 : 0;
        const int bm3 = (b >= 3) ? b - 3 : 0;
        const int bp1 = (b + 1 < NB) ? b + 1 : NB - 1;
        const int bp2 = (b + 2 < NB) ? b + 2 : NB - 1;
        const int bp3 = (b + 3 < NB) ? b + 3 : NB - 1;

        // mask inputs: unconditional loads, value-select for OOB
        const float a1 = (b >= 1)      ? (float)nm[bm1 * NC + c] : 0.f;
        const float a2 = (b >= 2)      ? (float)nm[bm2 * NC + c] : 0.f;
        const float a3 = (b >= 3)      ? (float)nm[bm3 * NC + c] : 0.f;
        const float r0 =                 (float)nm[b   * NC + c];
        const float r1 = (b + 1 < NB)  ? (float)nm[bp1 * NC + c] : 0.f;
        const float r2 = (b + 2 < NB)  ? (float)nm[bp2 * NC + c] : 0.f;

        // effective masks: cumulative product x shifted-value validity
        float em[6];
        em[0] = a1;
        em[1] = a1 * a2;
        em[2] = a1 * a2 * a3;
        em[3] = (b + 1 < NB) ? r0 : 0.f;
        em[4] = (b + 2 < NB) ? r0 * r1 : 0.f;
        em[5] = (b + 3 < NB) ? r0 * r1 * r2 : 0.f;

        const int gbs[6] = {bm1, bm2, bm3, bp1, bp2, bp3};
        float4 v[6];
#pragma unroll
        for (int p = 0; p < 6; ++p)
            v[p] = *reinterpret_cast<const float4*>(
                e + ((size_t)gbs[p] * NC + c) * ND + l * 4);

        f32x4 acc = (f32x4){0.f, 0.f, 0.f, 0.f};
#pragma unroll
        for (int p = 0; p < 6; ++p) {
            acc[0] = fmaf(em[p], v[p].x, acc[0]);
            acc[1] = fmaf(em[p], v[p].y, acc[1]);
            acc[2] = fmaf(em[p], v[p].z, acc[2]);
            acc[3] = fmaf(em[p], v[p].w, acc[3]);
        }
        const float s6 = 1.0f / 6.0f;
        f32x4 r;
        r[0] = acc[0] * s6; r[1] = acc[1] * s6;
        r[2] = acc[2] * s6; r[3] = acc[3] * s6;
        *reinterpret_cast<f32x4a*>(out + (size_t)nrow * OUTW + l * 4) = r;
        return;
    }

    // ================= SIM role: 2 waves per b (left/right) =================
    const int b    = (xcd * SIMB + idx) * 4 + (w >> 1);
    const int side = w & 1;                   // 0 = left (-1,-2,-3), 1 = right
    const int col  = l & 15, hi = l >> 4;
    const int koff = hi * 8;

    // per-col cumulative masks with validity folded in (em)
    float em[3];
    int gbc[3];                               // clamped neighbor b's
    if (side == 0) {
        const int bm1 = (b >= 1) ? b - 1 : 0;
        const int bm2 = (b >= 2) ? b - 2 : 0;
        const int bm3 = (b >= 3) ? b - 3 : 0;
        const float a1 = (b >= 1) ? (float)nm[bm1 * NC + col] : 0.f;
        const float a2 = (b >= 2) ? (float)nm[bm2 * NC + col] : 0.f;
        const float a3 = (b >= 3) ? (float)nm[bm3 * NC + col] : 0.f;
        em[0] = a1; em[1] = a1 * a2; em[2] = a1 * a2 * a3;
        gbc[0] = bm1; gbc[1] = bm2; gbc[2] = bm3;
    } else {
        const int bp1 = (b + 1 < NB) ? b + 1 : NB - 1;
        const int bp2 = (b + 2 < NB) ? b + 2 : NB - 1;
        const int bp3 = (b + 3 < NB) ? b + 3 : NB - 1;
        const float a0 = (float)nm[b * NC + col];
        const float a1 = (b + 1 < NB) ? (float)nm[bp1 * NC + col] : 0.f;
        const float a2 = (b + 2 < NB) ? (float)nm[bp2 * NC + col] : 0.f;
        em[0] = (b + 1 < NB) ? a0 : 0.f;
        em[1] = (b + 2 < NB) ? a0 * a1 : 0.f;
        em[2] = (b + 3 < NB) ? a0 * a1 * a2 : 0.f;
        gbc[0] = bp1; gbc[1] = bp2; gbc[2] = bp3;
    }

    // own tile -> A-frags + exact fp32 norm
    const float* rp0 = e + ((size_t)b * NC + col) * ND + koff;
    float4 s[16];
#pragma unroll
    for (int c = 0; c < 8; ++c) {
        s[2 * c]     = *reinterpret_cast<const float4*>(rp0 + c * 32);
        s[2 * c + 1] = *reinterpret_cast<const float4*>(rp0 + c * 32 + 4);
    }
    bf16x8 af[8];
    float ssq = 0.f;
#pragma unroll
    for (int c = 0; c < 8; ++c) {
        const float4 a = s[2 * c], bb = s[2 * c + 1];
        af[c] = cvt8(a, bb);
        ssq = fmaf(a.x, a.x, ssq);  ssq = fmaf(a.y, a.y, ssq);
        ssq = fmaf(a.z, a.z, ssq);  ssq = fmaf(a.w, a.w, ssq);
        ssq = fmaf(bb.x, bb.x, ssq); ssq = fmaf(bb.y, bb.y, ssq);
        ssq = fmaf(bb.z, bb.z, ssq); ssq = fmaf(bb.w, bb.w, ssq);
    }
    ssq += __shfl_xor(ssq, 16, 64);
    ssq += __shfl_xor(ssq, 32, 64);
    const float nrm_own = sqrtf(ssq);

    f32x4 acc[3];
    float nbn[3];
#pragma unroll
    for (int pp = 0; pp < 3; ++pp) {
        acc[pp] = (f32x4){0.f, 0.f, 0.f, 0.f};
        const float* rp = e + ((size_t)gbc[pp] * NC + col) * ND + koff;
#pragma unroll
        for (int c = 0; c < 8; ++c) {
            s[2 * c]     = *reinterpret_cast<const float4*>(rp + c * 32);
            s[2 * c + 1] = *reinterpret_cast<const float4*>(rp + c * 32 + 4);
        }
        float sq = 0.f;
#pragma unroll
        for (int c = 0; c < 8; ++c) {
            const float4 a = s[2 * c], bb = s[2 * c + 1];
            bf16x8 bf = cvt8(a, bb);
            acc[pp] = __builtin_amdgcn_mfma_f32_16x16x32_bf16(af[c], bf, acc[pp], 0, 0, 0);
            sq = fmaf(a.x, a.x, sq);  sq = fmaf(a.y, a.y, sq);
            sq = fmaf(a.z, a.z, sq);  sq = fmaf(a.w, a.w, sq);
            sq = fmaf(bb.x, bb.x, sq); sq = fmaf(bb.y, bb.y, sq);
            sq = fmaf(bb.z, bb.z, sq); sq = fmaf(bb.w, bb.w, sq);
        }
        sq += __shfl_xor(sq, 16, 64);
        sq += __shfl_xor(sq, 32, 64);
        nbn[pp] = sq > 0.f ? sqrtf(sq) : 0.f;
    }

    float na[4];
#pragma unroll
    for (int r = 0; r < 4; ++r) na[r] = __shfl(nrm_own, hi * 4 + r, 16);

    float sim[3][4];
    float rowsum[4] = {0.f, 0.f, 0.f, 0.f};
#pragma unroll
    for (int pp = 0; pp < 3; ++pp) {
        const bool mv = (em[pp] != 0.f);
#pragma unroll
        for (int r = 0; r < 4; ++r) {
            float qd = acc[pp][r] / fmaxf(na[r] * nbn[pp], 1e-8f);
            float sv = (mv && qd > THRED) ? fminf(qd, 1.f) : 0.f;
            sim[pp][r] = sv;
            rowsum[r] += sv;
        }
    }
#pragma unroll
    for (int r = 0; r < 4; ++r) {
#pragma unroll
        for (int o = 1; o < 16; o <<= 1) rowsum[r] += __shfl_xor(rowsum[r], o, 16);
    }

    // combine left+right row sums across the wave pair
    if (col == 0) {
#pragma unroll
        for (int r = 0; r < 4; ++r) lsum[w][hi * 4 + r] = rowsum[r];
    }
    __syncthreads();

    const int p_base = side * 3;
#pragma unroll
    for (int r = 0; r < 4; ++r) {
        const float tot = rowsum[r] + lsum[w ^ 1][hi * 4 + r];
        const float inv = 1.0f / fmaxf(tot + 1.0f, 1e-12f);
        float* orow = out + (size_t)(b * NC + hi * 4 + r) * OUTW;
#pragma unroll
        for (int pp = 0; pp < 3; ++pp)
            orow[ND + (p_base + pp) * NC + col] = sim[pp][r] * inv;
        if (side == 0 && col == 0) orow[ND + 96] = inv;
    }
}

extern "C" void kernel_launch(void* const* d_in, const int* in_sizes, int n_in,
                              void* d_out, int out_size, void* d_ws, size_t ws_size,
                              hipStream_t stream) {
    const float* e = (const float*)d_in[0];
    const int* nmv = (const int*)d_in[1];
    float* out     = (float*)d_out;
    fused_kernel<<<NBLK, 512, 0, stream>>>(e, nmv, out);
}

// Round 6
// 49.941 us; speedup vs baseline: 1.3084x; 1.3084x over previous
//
#include <hip/hip_runtime.h>

#define NB 2048
#define NC 16
#define ND 256
#define OUTW 353
#define THRED 0.8f

typedef short bf16x8 __attribute__((ext_vector_type(8)));
typedef float f32x4 __attribute__((ext_vector_type(4)));
typedef float f32x4a __attribute__((ext_vector_type(4), aligned(4)));

__device__ __forceinline__ short f2s(float x) {      // native cast -> v_cvt_pk_bf16_f32
    __bf16 h = (__bf16)x;
    return __builtin_bit_cast(short, h);
}

__device__ __forceinline__ bf16x8 cvt8(const float4& a, const float4& b) {
    bf16x8 r;
    r[0] = f2s(a.x); r[1] = f2s(a.y); r[2] = f2s(a.z); r[3] = f2s(a.w);
    r[4] = f2s(b.x); r[5] = f2s(b.y); r[6] = f2s(b.z); r[7] = f2s(b.w);
    return r;
}

// One block (256 thr = 4 waves) per b. Wave q owns K-quarter [64q, 64q+64).
// Each wave: load 7 quarter-tiles -> MFMA partial dots + fp32 ssq partial +
// fp32 masked neigh accum (disjoint dims -> direct stores). Cross-wave
// combine of acc/ssq through padded LDS; wave 0 does the sim epilogue.
__global__ __launch_bounds__(256, 4) void fused_kernel(const float* __restrict__ e,
                                                       const int* __restrict__ nm,
                                                       float* __restrict__ out) {
    __shared__ float red[4][64][33];   // [wave][lane][24 acc + 7 ssq], +pad

    const int bid = blockIdx.x;
    const int b   = (bid & 7) * 256 + (bid >> 3);    // XCD-chunked, bijective
    const int q   = threadIdx.x >> 6;                // K-quarter
    const int l   = threadIdx.x & 63;
    const int col = l & 15, hi = l >> 4;
    const int koff = q * 64 + hi * 8;                // lane k-base (chunk 0); chunk 1 at +32

    // ---- clamped neighbor indices + effective cumulative masks (per lane col) ----
    const int bm1 = (b >= 1) ? b - 1 : 0;
    const int bm2 = (b >= 2) ? b - 2 : 0;
    const int bm3 = (b >= 3) ? b - 3 : 0;
    const int bp1 = (b + 1 < NB) ? b + 1 : NB - 1;
    const int bp2 = (b + 2 < NB) ? b + 2 : NB - 1;
    const int bp3 = (b + 3 < NB) ? b + 3 : NB - 1;

    const float a1 = (b >= 1) ? (float)nm[bm1 * NC + col] : 0.f;
    const float a2 = (b >= 2) ? (float)nm[bm2 * NC + col] : 0.f;
    const float a3 = (b >= 3) ? (float)nm[bm3 * NC + col] : 0.f;
    const float r0 = (float)nm[b * NC + col];
    const float r1 = (b + 1 < NB) ? (float)nm[bp1 * NC + col] : 0.f;
    const float r2 = (b + 2 < NB) ? (float)nm[bp2 * NC + col] : 0.f;

    float em[6];
    em[0] = a1;
    em[1] = a1 * a2;
    em[2] = a1 * a2 * a3;
    em[3] = (b + 1 < NB) ? r0 : 0.f;
    em[4] = (b + 2 < NB) ? r0 * r1 : 0.f;
    em[5] = (b + 3 < NB) ? r0 * r1 * r2 : 0.f;

    const int gbs[6] = {bm1, bm2, bm3, bp1, bp2, bp3};

    // ---- own quarter-tile: A-frags + ssq partial ----
    const float* rp0 = e + ((size_t)b * NC + col) * ND + koff;
    float4 s0 = *reinterpret_cast<const float4*>(rp0);
    float4 s1 = *reinterpret_cast<const float4*>(rp0 + 4);
    float4 s2 = *reinterpret_cast<const float4*>(rp0 + 32);
    float4 s3 = *reinterpret_cast<const float4*>(rp0 + 36);
    bf16x8 af0 = cvt8(s0, s1);
    bf16x8 af1 = cvt8(s2, s3);

    float ssqp[7];
    {
        float sq = 0.f;
        sq = fmaf(s0.x, s0.x, sq); sq = fmaf(s0.y, s0.y, sq);
        sq = fmaf(s0.z, s0.z, sq); sq = fmaf(s0.w, s0.w, sq);
        sq = fmaf(s1.x, s1.x, sq); sq = fmaf(s1.y, s1.y, sq);
        sq = fmaf(s1.z, s1.z, sq); sq = fmaf(s1.w, s1.w, sq);
        sq = fmaf(s2.x, s2.x, sq); sq = fmaf(s2.y, s2.y, sq);
        sq = fmaf(s2.z, s2.z, sq); sq = fmaf(s2.w, s2.w, sq);
        sq = fmaf(s3.x, s3.x, sq); sq = fmaf(s3.y, s3.y, sq);
        sq = fmaf(s3.z, s3.z, sq); sq = fmaf(s3.w, s3.w, sq);
        ssqp[0] = sq;
    }

    // ---- 6 neighbor quarter-tiles ----
    f32x4 acc[6];
    float nacc[16];
#pragma unroll
    for (int k = 0; k < 16; ++k) nacc[k] = 0.f;

#pragma unroll
    for (int p = 0; p < 6; ++p) {
        const float* rp = e + ((size_t)gbs[p] * NC + col) * ND + koff;
        float4 t0 = *reinterpret_cast<const float4*>(rp);
        float4 t1 = *reinterpret_cast<const float4*>(rp + 4);
        float4 t2 = *reinterpret_cast<const float4*>(rp + 32);
        float4 t3 = *reinterpret_cast<const float4*>(rp + 36);
        bf16x8 bf0 = cvt8(t0, t1);
        bf16x8 bf1 = cvt8(t2, t3);
        f32x4 ac = (f32x4){0.f, 0.f, 0.f, 0.f};
        ac = __builtin_amdgcn_mfma_f32_16x16x32_bf16(af0, bf0, ac, 0, 0, 0);
        ac = __builtin_amdgcn_mfma_f32_16x16x32_bf16(af1, bf1, ac, 0, 0, 0);
        acc[p] = ac;

        float sq = 0.f;
        sq = fmaf(t0.x, t0.x, sq); sq = fmaf(t0.y, t0.y, sq);
        sq = fmaf(t0.z, t0.z, sq); sq = fmaf(t0.w, t0.w, sq);
        sq = fmaf(t1.x, t1.x, sq); sq = fmaf(t1.y, t1.y, sq);
        sq = fmaf(t1.z, t1.z, sq); sq = fmaf(t1.w, t1.w, sq);
        sq = fmaf(t2.x, t2.x, sq); sq = fmaf(t2.y, t2.y, sq);
        sq = fmaf(t2.z, t2.z, sq); sq = fmaf(t2.w, t2.w, sq);
        sq = fmaf(t3.x, t3.x, sq); sq = fmaf(t3.y, t3.y, sq);
        sq = fmaf(t3.z, t3.z, sq); sq = fmaf(t3.w, t3.w, sq);
        ssqp[1 + p] = sq;

        const float m = em[p];
        nacc[0]  = fmaf(m, t0.x, nacc[0]);  nacc[1]  = fmaf(m, t0.y, nacc[1]);
        nacc[2]  = fmaf(m, t0.z, nacc[2]);  nacc[3]  = fmaf(m, t0.w, nacc[3]);
        nacc[4]  = fmaf(m, t1.x, nacc[4]);  nacc[5]  = fmaf(m, t1.y, nacc[5]);
        nacc[6]  = fmaf(m, t1.z, nacc[6]);  nacc[7]  = fmaf(m, t1.w, nacc[7]);
        nacc[8]  = fmaf(m, t2.x, nacc[8]);  nacc[9]  = fmaf(m, t2.y, nacc[9]);
        nacc[10] = fmaf(m, t2.z, nacc[10]); nacc[11] = fmaf(m, t2.w, nacc[11]);
        nacc[12] = fmaf(m, t3.x, nacc[12]); nacc[13] = fmaf(m, t3.y, nacc[13]);
        nacc[14] = fmaf(m, t3.z, nacc[14]); nacc[15] = fmaf(m, t3.w, nacc[15]);
    }

    // ---- neigh store: lane owns row `col`, dims koff..koff+7 and koff+32..+39 ----
    {
        const float s6 = 1.0f / 6.0f;
        float* nrow = out + (size_t)(b * NC + col) * OUTW + koff;
        f32x4 v;
        v[0] = nacc[0] * s6;  v[1] = nacc[1] * s6;  v[2] = nacc[2] * s6;  v[3] = nacc[3] * s6;
        *reinterpret_cast<f32x4a*>(nrow) = v;
        v[0] = nacc[4] * s6;  v[1] = nacc[5] * s6;  v[2] = nacc[6] * s6;  v[3] = nacc[7] * s6;
        *reinterpret_cast<f32x4a*>(nrow + 4) = v;
        v[0] = nacc[8] * s6;  v[1] = nacc[9] * s6;  v[2] = nacc[10] * s6; v[3] = nacc[11] * s6;
        *reinterpret_cast<f32x4a*>(nrow + 32) = v;
        v[0] = nacc[12] * s6; v[1] = nacc[13] * s6; v[2] = nacc[14] * s6; v[3] = nacc[15] * s6;
        *reinterpret_cast<f32x4a*>(nrow + 36) = v;
    }

    // ---- cross-wave reduction through LDS ----
    {
        float* myred = &red[q][l][0];
#pragma unroll
        for (int p = 0; p < 6; ++p) {
#pragma unroll
            for (int r = 0; r < 4; ++r) myred[p * 4 + r] = acc[p][r];
        }
#pragma unroll
        for (int tt = 0; tt < 7; ++tt) myred[24 + tt] = ssqp[tt];
    }
    __syncthreads();
    if (q != 0) return;

    // ---- wave 0: combine quarters ----
#pragma unroll
    for (int ww = 1; ww < 4; ++ww) {
        const float* o = &red[ww][l][0];
#pragma unroll
        for (int p = 0; p < 6; ++p) {
#pragma unroll
            for (int r = 0; r < 4; ++r) acc[p][r] += o[p * 4 + r];
        }
#pragma unroll
        for (int tt = 0; tt < 7; ++tt) ssqp[tt] += o[24 + tt];
    }

    // full row ssq: sum over hi groups (col preserved)
    float norms[7];
#pragma unroll
    for (int tt = 0; tt < 7; ++tt) {
        float v = ssqp[tt];
        v += __shfl_xor(v, 16, 64);
        v += __shfl_xor(v, 32, 64);
        norms[tt] = sqrtf(v);
    }

    float na[4];
#pragma unroll
    for (int r = 0; r < 4; ++r) na[r] = __shfl(norms[0], hi * 4 + r, 16);

    float sim[6][4];
    float rowsum[4] = {0.f, 0.f, 0.f, 0.f};
#pragma unroll
    for (int p = 0; p < 6; ++p) {
        const bool mv = (em[p] != 0.f);
        const float nbv = norms[1 + p];
#pragma unroll
        for (int r = 0; r < 4; ++r) {
            float qd = acc[p][r] / fmaxf(na[r] * nbv, 1e-8f);
            float sv = (mv && qd > THRED) ? fminf(qd, 1.f) : 0.f;
            sim[p][r] = sv;
            rowsum[r] += sv;
        }
    }
#pragma unroll
    for (int r = 0; r < 4; ++r) {
#pragma unroll
        for (int o = 1; o < 16; o <<= 1) rowsum[r] += __shfl_xor(rowsum[r], o, 16);
    }

#pragma unroll
    for (int r = 0; r < 4; ++r) {
        const float inv = 1.0f / fmaxf(rowsum[r] + 1.0f, 1e-12f);
        float* orow = out + (size_t)(b * NC + hi * 4 + r) * OUTW;
#pragma unroll
        for (int p = 0; p < 6; ++p)
            orow[ND + p * NC + col] = sim[p][r] * inv;
        if (col == 0) orow[ND + 96] = inv;
    }
}

extern "C" void kernel_launch(void* const* d_in, const int* in_sizes, int n_in,
                              void* d_out, int out_size, void* d_ws, size_t ws_size,
                              hipStream_t stream) {
    const float* e = (const float*)d_in[0];
    const int* nmv = (const int*)d_in[1];
    float* out     = (float*)d_out;
    fused_kernel<<<NB, 256, 0, stream>>>(e, nmv, out);
}

// Round 7
// 45.459 us; speedup vs baseline: 1.4374x; 1.0986x over previous
//
#include <hip/hip_runtime.h>

#define NB 2048
#define NC 16
#define ND 256
#define OUTW 353
#define THRED 0.8f

typedef short bf16x8 __attribute__((ext_vector_type(8)));
typedef float f32x4 __attribute__((ext_vector_type(4)));
typedef float f32x4a __attribute__((ext_vector_type(4), aligned(4)));

__device__ __forceinline__ short f2s(float x) {      // native cast -> v_cvt_pk_bf16_f32
    __bf16 h = (__bf16)x;
    return __builtin_bit_cast(short, h);
}

__device__ __forceinline__ bf16x8 cvt8(const float4& a, const float4& b) {
    bf16x8 r;
    r[0] = f2s(a.x); r[1] = f2s(a.y); r[2] = f2s(a.z); r[3] = f2s(a.w);
    r[4] = f2s(b.x); r[5] = f2s(b.y); r[6] = f2s(b.z); r[7] = f2s(b.w);
    return r;
}

// One block (256 thr = 4 waves) per b. Wave q owns K-quarter [64q, 64q+64).
// launch_bounds (256,3): VGPR cap ~170 so nothing spills (R6's (256,4) spilled
// ~70 MB of scratch -> WRITE_SIZE 116 MB). Wave-0 epilogue is two-pass over
// sims so only the summed acc (24 regs) stays live.
__global__ __launch_bounds__(256, 3) void fused_kernel(const float* __restrict__ e,
                                                       const int* __restrict__ nm,
                                                       float* __restrict__ out) {
    __shared__ float red[4][64][33];   // [wave][lane][24 acc + 7 ssq], pad->conflict-free

    const int bid = blockIdx.x;
    const int b   = (bid & 7) * 256 + (bid >> 3);    // XCD-chunked, bijective
    const int q   = threadIdx.x >> 6;                // K-quarter
    const int l   = threadIdx.x & 63;
    const int col = l & 15, hi = l >> 4;
    const int koff = q * 64 + hi * 8;                // chunk0; chunk1 at +32

    // ---- clamped neighbor indices + effective cumulative masks (per lane col) ----
    const int bm1 = (b >= 1) ? b - 1 : 0;
    const int bm2 = (b >= 2) ? b - 2 : 0;
    const int bm3 = (b >= 3) ? b - 3 : 0;
    const int bp1 = (b + 1 < NB) ? b + 1 : NB - 1;
    const int bp2 = (b + 2 < NB) ? b + 2 : NB - 1;
    const int bp3 = (b + 3 < NB) ? b + 3 : NB - 1;

    const float a1 = (b >= 1) ? (float)nm[bm1 * NC + col] : 0.f;
    const float a2 = (b >= 2) ? (float)nm[bm2 * NC + col] : 0.f;
    const float a3 = (b >= 3) ? (float)nm[bm3 * NC + col] : 0.f;
    const float r0 = (float)nm[b * NC + col];
    const float r1 = (b + 1 < NB) ? (float)nm[bp1 * NC + col] : 0.f;
    const float r2 = (b + 2 < NB) ? (float)nm[bp2 * NC + col] : 0.f;

    float em[6];
    em[0] = a1;
    em[1] = a1 * a2;
    em[2] = a1 * a2 * a3;
    em[3] = (b + 1 < NB) ? r0 : 0.f;
    em[4] = (b + 2 < NB) ? r0 * r1 : 0.f;
    em[5] = (b + 3 < NB) ? r0 * r1 * r2 : 0.f;

    const int gbs[6] = {bm1, bm2, bm3, bp1, bp2, bp3};

    // ---- own quarter-tile: A-frags + ssq partial ----
    const float* rp0 = e + ((size_t)b * NC + col) * ND + koff;
    float4 s0 = *reinterpret_cast<const float4*>(rp0);
    float4 s1 = *reinterpret_cast<const float4*>(rp0 + 4);
    float4 s2 = *reinterpret_cast<const float4*>(rp0 + 32);
    float4 s3 = *reinterpret_cast<const float4*>(rp0 + 36);
    bf16x8 af0 = cvt8(s0, s1);
    bf16x8 af1 = cvt8(s2, s3);

    float ssq_own;
    {
        float sq = 0.f;
        sq = fmaf(s0.x, s0.x, sq); sq = fmaf(s0.y, s0.y, sq);
        sq = fmaf(s0.z, s0.z, sq); sq = fmaf(s0.w, s0.w, sq);
        sq = fmaf(s1.x, s1.x, sq); sq = fmaf(s1.y, s1.y, sq);
        sq = fmaf(s1.z, s1.z, sq); sq = fmaf(s1.w, s1.w, sq);
        sq = fmaf(s2.x, s2.x, sq); sq = fmaf(s2.y, s2.y, sq);
        sq = fmaf(s2.z, s2.z, sq); sq = fmaf(s2.w, s2.w, sq);
        sq = fmaf(s3.x, s3.x, sq); sq = fmaf(s3.y, s3.y, sq);
        sq = fmaf(s3.z, s3.z, sq); sq = fmaf(s3.w, s3.w, sq);
        ssq_own = sq;
    }

    // ---- 6 neighbor quarter-tiles: MFMA + ssq + masked neigh accum ----
    float nacc[16];
#pragma unroll
    for (int k = 0; k < 16; ++k) nacc[k] = 0.f;

    float* myred = &red[q][l][0];

#pragma unroll
    for (int p = 0; p < 6; ++p) {
        const float* rp = e + ((size_t)gbs[p] * NC + col) * ND + koff;
        float4 t0 = *reinterpret_cast<const float4*>(rp);
        float4 t1 = *reinterpret_cast<const float4*>(rp + 4);
        float4 t2 = *reinterpret_cast<const float4*>(rp + 32);
        float4 t3 = *reinterpret_cast<const float4*>(rp + 36);
        bf16x8 bf0 = cvt8(t0, t1);
        bf16x8 bf1 = cvt8(t2, t3);
        f32x4 ac = (f32x4){0.f, 0.f, 0.f, 0.f};
        ac = __builtin_amdgcn_mfma_f32_16x16x32_bf16(af0, bf0, ac, 0, 0, 0);
        ac = __builtin_amdgcn_mfma_f32_16x16x32_bf16(af1, bf1, ac, 0, 0, 0);
        // park partials in LDS immediately -> acc regs don't stay live
        myred[p * 4 + 0] = ac[0];
        myred[p * 4 + 1] = ac[1];
        myred[p * 4 + 2] = ac[2];
        myred[p * 4 + 3] = ac[3];

        float sq = 0.f;
        sq = fmaf(t0.x, t0.x, sq); sq = fmaf(t0.y, t0.y, sq);
        sq = fmaf(t0.z, t0.z, sq); sq = fmaf(t0.w, t0.w, sq);
        sq = fmaf(t1.x, t1.x, sq); sq = fmaf(t1.y, t1.y, sq);
        sq = fmaf(t1.z, t1.z, sq); sq = fmaf(t1.w, t1.w, sq);
        sq = fmaf(t2.x, t2.x, sq); sq = fmaf(t2.y, t2.y, sq);
        sq = fmaf(t2.z, t2.z, sq); sq = fmaf(t2.w, t2.w, sq);
        sq = fmaf(t3.x, t3.x, sq); sq = fmaf(t3.y, t3.y, sq);
        sq = fmaf(t3.z, t3.z, sq); sq = fmaf(t3.w, t3.w, sq);
        myred[24 + 1 + p] = sq;

        const float m = em[p];
        nacc[0]  = fmaf(m, t0.x, nacc[0]);  nacc[1]  = fmaf(m, t0.y, nacc[1]);
        nacc[2]  = fmaf(m, t0.z, nacc[2]);  nacc[3]  = fmaf(m, t0.w, nacc[3]);
        nacc[4]  = fmaf(m, t1.x, nacc[4]);  nacc[5]  = fmaf(m, t1.y, nacc[5]);
        nacc[6]  = fmaf(m, t1.z, nacc[6]);  nacc[7]  = fmaf(m, t1.w, nacc[7]);
        nacc[8]  = fmaf(m, t2.x, nacc[8]);  nacc[9]  = fmaf(m, t2.y, nacc[9]);
        nacc[10] = fmaf(m, t2.z, nacc[10]); nacc[11] = fmaf(m, t2.w, nacc[11]);
        nacc[12] = fmaf(m, t3.x, nacc[12]); nacc[13] = fmaf(m, t3.y, nacc[13]);
        nacc[14] = fmaf(m, t3.z, nacc[14]); nacc[15] = fmaf(m, t3.w, nacc[15]);
    }
    myred[24] = ssq_own;

    // ---- neigh store: lane owns row `col`, dims koff..+7 and koff+32..+39 ----
    {
        const float s6 = 1.0f / 6.0f;
        float* nrow = out + (size_t)(b * NC + col) * OUTW + koff;
        f32x4 v;
        v[0] = nacc[0] * s6;  v[1] = nacc[1] * s6;  v[2] = nacc[2] * s6;  v[3] = nacc[3] * s6;
        *reinterpret_cast<f32x4a*>(nrow) = v;
        v[0] = nacc[4] * s6;  v[1] = nacc[5] * s6;  v[2] = nacc[6] * s6;  v[3] = nacc[7] * s6;
        *reinterpret_cast<f32x4a*>(nrow + 4) = v;
        v[0] = nacc[8] * s6;  v[1] = nacc[9] * s6;  v[2] = nacc[10] * s6; v[3] = nacc[11] * s6;
        *reinterpret_cast<f32x4a*>(nrow + 32) = v;
        v[0] = nacc[12] * s6; v[1] = nacc[13] * s6; v[2] = nacc[14] * s6; v[3] = nacc[15] * s6;
        *reinterpret_cast<f32x4a*>(nrow + 36) = v;
    }

    __syncthreads();
    if (q != 0) return;

    // ================= wave-0 epilogue (slim) =================
    // norms (7 per lane-col)
    float norms[7];
#pragma unroll
    for (int tt = 0; tt < 7; ++tt) {
        float v = red[0][l][24 + tt] + red[1][l][24 + tt]
                + red[2][l][24 + tt] + red[3][l][24 + tt];
        v += __shfl_xor(v, 16, 64);
        v += __shfl_xor(v, 32, 64);
        norms[tt] = sqrtf(v);
    }
    float na[4];
#pragma unroll
    for (int r = 0; r < 4; ++r) na[r] = __shfl(norms[0], hi * 4 + r, 16);

    // summed acc (one LDS read pass, 24 regs)
    float acc[24];
#pragma unroll
    for (int k = 0; k < 24; ++k)
        acc[k] = red[0][l][k] + red[1][l][k] + red[2][l][k] + red[3][l][k];

    // pass 1: rowsum
    float rowsum[4] = {0.f, 0.f, 0.f, 0.f};
#pragma unroll
    for (int p = 0; p < 6; ++p) {
        const bool mv = (em[p] != 0.f);
        const float nbv = norms[1 + p];
#pragma unroll
        for (int r = 0; r < 4; ++r) {
            float qd = acc[p * 4 + r] / fmaxf(na[r] * nbv, 1e-8f);
            rowsum[r] += (mv && qd > THRED) ? fminf(qd, 1.f) : 0.f;
        }
    }
#pragma unroll
    for (int r = 0; r < 4; ++r) {
#pragma unroll
        for (int o = 1; o < 16; o <<= 1) rowsum[r] += __shfl_xor(rowsum[r], o, 16);
        rowsum[r] = 1.0f / fmaxf(rowsum[r] + 1.0f, 1e-12f);   // -> inv
    }

    // pass 2: recompute sims, scale, store
#pragma unroll
    for (int r = 0; r < 4; ++r) {
        float* orow = out + (size_t)(b * NC + hi * 4 + r) * OUTW;
#pragma unroll
        for (int p = 0; p < 6; ++p) {
            const bool mv = (em[p] != 0.f);
            float qd = acc[p * 4 + r] / fmaxf(na[r] * norms[1 + p], 1e-8f);
            float sv = (mv && qd > THRED) ? fminf(qd, 1.f) : 0.f;
            orow[ND + p * NC + col] = sv * rowsum[r];
        }
        if (col == 0) orow[ND + 96] = rowsum[r];
    }
}

extern "C" void kernel_launch(void* const* d_in, const int* in_sizes, int n_in,
                              void* d_out, int out_size, void* d_ws, size_t ws_size,
                              hipStream_t stream) {
    const float* e = (const float*)d_in[0];
    const int* nmv = (const int*)d_in[1];
    float* out     = (float*)d_out;
    fused_kernel<<<NB, 256, 0, stream>>>(e, nmv, out);
}